// Round 1
// baseline (376.013 us; speedup 1.0000x reference)
//
#include <hip/hip_runtime.h>
#include <cstdint>

// ---------- sizes ----------
#define BT_ROWS 4096      // B*T
#define DM      1024
#define DFF     2730
#define DFFP    2816      // padded to /128
#define TSEQ    2048
#define LDQKV   3072

typedef float  f32x4  __attribute__((ext_vector_type(4)));
typedef __bf16 bf16x8 __attribute__((ext_vector_type(8)));

typedef __attribute__((address_space(1))) const unsigned int as1_uint;
typedef __attribute__((address_space(3))) unsigned int       as3_uint;

__device__ __forceinline__ unsigned short f2bf(float f) {
  union { float f; unsigned int u; } v; v.f = f;
  unsigned int u = v.u;
  return (unsigned short)((u + 0x7fffu + ((u >> 16) & 1u)) >> 16);  // RNE
}
__device__ __forceinline__ float bf2f(unsigned int b) {
  union { unsigned int u; float f; } v; v.u = b << 16;
  return v.f;
}

__device__ __forceinline__ void async_cp16(const void* g, void* l) {
  // 16B-wide global->LDS DMA; LDS dest is wave-uniform base + lane*16
  __builtin_amdgcn_global_load_lds((as1_uint*)(uintptr_t)g, (as3_uint*)(uintptr_t)l, 16, 0, 0);
}

// ---------- weight convert (+optional zero pad) ----------
__global__ void cvt_pad_kernel(const float* __restrict__ src, unsigned short* __restrict__ dst,
                               int Rs, int Cs, long total, int Cd) {
  long idx = (long)blockIdx.x * 256 + threadIdx.x;
  if (idx >= total) return;
  int r = (int)(idx / Cd), c = (int)(idx % Cd);
  float v = (r < Rs && c < Cs) ? src[(long)r * Cs + c] : 0.f;
  dst[idx] = f2bf(v);
}

// ---------- RMSNorm (fp32 in -> bf16 out), one block per row ----------
__global__ void rmsnorm_kernel(const float* __restrict__ x, const float* __restrict__ g,
                               unsigned short* __restrict__ out) {
  const int row = blockIdx.x, tid = threadIdx.x;
  const float4 xv = reinterpret_cast<const float4*>(x + (long)row * DM)[tid];
  float ss = xv.x * xv.x + xv.y * xv.y + xv.z * xv.z + xv.w * xv.w;
#pragma unroll
  for (int o = 32; o > 0; o >>= 1) ss += __shfl_xor(ss, o);
  __shared__ float wsum[4];
  if ((tid & 63) == 0) wsum[tid >> 6] = ss;
  __syncthreads();
  const float inv = rsqrtf((wsum[0] + wsum[1] + wsum[2] + wsum[3]) * (1.f / DM) + 1e-5f);
  const float4 gv = reinterpret_cast<const float4*>(g)[tid];
  ushort4 o4;
  o4.x = f2bf(xv.x * inv * gv.x);
  o4.y = f2bf(xv.y * inv * gv.y);
  o4.z = f2bf(xv.z * inv * gv.z);
  o4.w = f2bf(xv.w * inv * gv.w);
  reinterpret_cast<ushort4*>(out + (long)row * DM)[tid] = o4;
}

// ---------- RoPE cos/sin table ----------
__global__ void trig_kernel(const int* __restrict__ pos, float* __restrict__ ct, float* __restrict__ st) {
  int idx = blockIdx.x * 256 + threadIdx.x;
  if (idx >= BT_ROWS * 32) return;
  int r = idx >> 5, i = idx & 31;
  float f = powf(10000.f, -(float)(2 * i) * (1.f / 64.f));
  float ang = (float)pos[r] * f;
  float sv, cv;
  sincosf(ang, &sv, &cv);
  ct[idx] = cv; st[idx] = sv;
}

// ---------- RoPE applied in-place to Q,K halves of QKV (bf16) ----------
__global__ void rope_kernel(unsigned short* __restrict__ QKV,
                            const float* __restrict__ ct, const float* __restrict__ st) {
  int idx = blockIdx.x * 256 + threadIdx.x;  // over 4096*512 (row, head*pair)
  if (idx >= BT_ROWS * 512) return;
  int r = idx >> 9, p = idx & 511;
  int h = p >> 5, i = p & 31;
  float c = ct[r * 32 + i], s = st[r * 32 + i];
  unsigned int* base = reinterpret_cast<unsigned int*>(QKV + (long)r * LDQKV + h * 64 + 2 * i);
  unsigned int q01 = base[0];
  float x0 = bf2f(q01 & 0xffffu), x1 = bf2f(q01 >> 16);
  base[0] = (unsigned int)f2bf(c * x0 - s * x1) | ((unsigned int)f2bf(s * x0 + c * x1) << 16);
  unsigned int k01 = base[512];  // +1024 ushorts = K block
  float y0 = bf2f(k01 & 0xffffu), y1 = bf2f(k01 >> 16);
  base[512] = (unsigned int)f2bf(c * y0 - s * y1) | ((unsigned int)f2bf(s * y0 + c * y1) << 16);
}

// ---------- GEMM: C[M,N] = A[M,K] * B[N,K]^T  (bf16 in, fp32 acc) ----------
// EPI 0: bf16 store; EPI 1: fp32 store of acc + resid
template <int EPI>
__global__ __launch_bounds__(256) void gemm_bt(
    const unsigned short* __restrict__ A, const unsigned short* __restrict__ B,
    void* __restrict__ C, const float* __restrict__ resid,
    int M, int N, int K, int ldc) {
  __shared__ unsigned short As[128 * 32];
  __shared__ unsigned short Bs[128 * 32];
  const int tid = threadIdx.x;
  const int wid = tid >> 6;
  const int lane = tid & 63;
  const long rowBase = (long)blockIdx.y * 128;
  const long colBase = (long)blockIdx.x * 128;
  const int wm = (wid >> 1) * 64;
  const int wn = (wid & 1) * 64;
  const int l4 = lane >> 2;        // staging: row within 16-row chunk
  const int c8 = (lane & 3) * 8;   // staging: col (8 bf16 = 16B)
  const int fr = lane & 15;        // fragment row
  const int fg = lane >> 4;        // fragment k-group

  const f32x4 z4 = {0.f, 0.f, 0.f, 0.f};
  f32x4 acc[4][4];
#pragma unroll
  for (int m = 0; m < 4; ++m)
#pragma unroll
    for (int n = 0; n < 4; ++n) acc[m][n] = z4;

  const int nkt = K >> 5;
  for (int kt = 0; kt < nkt; ++kt) {
    if (kt) __syncthreads();  // previous compute done before LDS overwrite
    const long kOff = (long)kt * 32 + c8;
#pragma unroll
    for (int c = 0; c < 2; ++c) {
      const int chunk = c * 4 + wid;  // wave-uniform LDS base
      async_cp16(A + (rowBase + chunk * 16 + l4) * K + kOff, &As[chunk * 512]);
      async_cp16(B + (colBase + chunk * 16 + l4) * K + kOff, &Bs[chunk * 512]);
    }
    __syncthreads();  // compiler drains vmcnt(0) before s_barrier -> LDS ready
    bf16x8 af[4], bfr[4];
#pragma unroll
    for (int m = 0; m < 4; ++m)
      af[m] = *reinterpret_cast<const bf16x8*>(&As[(wm + m * 16 + fr) * 32 + fg * 8]);
#pragma unroll
    for (int n = 0; n < 4; ++n)
      bfr[n] = *reinterpret_cast<const bf16x8*>(&Bs[(wn + n * 16 + fr) * 32 + fg * 8]);
#pragma unroll
    for (int m = 0; m < 4; ++m)
#pragma unroll
      for (int n = 0; n < 4; ++n)
        acc[m][n] = __builtin_amdgcn_mfma_f32_16x16x32_bf16(af[m], bfr[n], acc[m][n], 0, 0, 0);
  }

  const int erow = fg * 4;  // C: col = lane&15, row = (lane>>4)*4 + reg
  if (EPI == 0) {
    unsigned short* Cp = (unsigned short*)C;
#pragma unroll
    for (int m = 0; m < 4; ++m) {
      const long r0 = rowBase + wm + m * 16 + erow;
#pragma unroll
      for (int n = 0; n < 4; ++n) {
        const long col = colBase + wn + n * 16 + fr;
#pragma unroll
        for (int r = 0; r < 4; ++r) Cp[(r0 + r) * ldc + col] = f2bf(acc[m][n][r]);
      }
    }
  } else {
    float* Cf = (float*)C;
#pragma unroll
    for (int m = 0; m < 4; ++m) {
      const long r0 = rowBase + wm + m * 16 + erow;
#pragma unroll
      for (int n = 0; n < 4; ++n) {
        const long col = colBase + wn + n * 16 + fr;
#pragma unroll
        for (int r = 0; r < 4; ++r) {
          const long o = (r0 + r) * ldc + col;
          Cf[o] = acc[m][n][r] + resid[o];
        }
      }
    }
  }
}

// ---------- flash attention, causal, 16 heads x d_k=64 ----------
// Swapped QK^T (S' = K*Q^T) with row-permuted K so P' lands directly in the
// PV MFMA's B-fragment layout (k_local = 8*(lane>>4)+j). One wave = 16 q rows.
__global__ __launch_bounds__(256) void attn_kernel(
    const unsigned short* __restrict__ QKV, unsigned short* __restrict__ O) {
  const int bh = blockIdx.x;
  const int b = bh >> 4, h = bh & 15;
  const int wid = threadIdx.x >> 6, lane = threadIdx.x & 63;
  const int qt = blockIdx.y * 4 + wid;  // 0..127
  const int qbase = qt * 16;
  const int fr = lane & 15, g = lane >> 4;
  const long rowb = (long)b * TSEQ;
  const int hoff = h * 64;

  const unsigned short* qrow = QKV + (rowb + qbase + fr) * LDQKV + hoff + g * 8;
  const bf16x8 qb0 = *reinterpret_cast<const bf16x8*>(qrow);
  const bf16x8 qb1 = *reinterpret_cast<const bf16x8*>(qrow + 32);

  const f32x4 z4 = {0.f, 0.f, 0.f, 0.f};
  f32x4 acc[4];
#pragma unroll
  for (int d = 0; d < 4; ++d) acc[d] = z4;
  float mrun = -1e30f, lrun = 0.f;
  const int kperm = 8 * (fr >> 2) + (fr & 3);  // S1 A-row permutation
  const int qg = qbase + fr;
  const int nkt = (qt >> 1) + 1;

  for (int kt = 0; kt < nkt; ++kt) {
    const int kbase = kt * 32;
    const unsigned short* k1 = QKV + (rowb + kbase + kperm) * LDQKV + 1024 + hoff + g * 8;
    const unsigned short* k2 = k1 + 4 * LDQKV;
    const bf16x8 ka0 = *reinterpret_cast<const bf16x8*>(k1);
    const bf16x8 ka1 = *reinterpret_cast<const bf16x8*>(k1 + 32);
    const bf16x8 kc0 = *reinterpret_cast<const bf16x8*>(k2);
    const bf16x8 kc1 = *reinterpret_cast<const bf16x8*>(k2 + 32);
    f32x4 s1 = z4, s2 = z4;
    s1 = __builtin_amdgcn_mfma_f32_16x16x32_bf16(ka0, qb0, s1, 0, 0, 0);
    s1 = __builtin_amdgcn_mfma_f32_16x16x32_bf16(ka1, qb1, s1, 0, 0, 0);
    s2 = __builtin_amdgcn_mfma_f32_16x16x32_bf16(kc0, qb0, s2, 0, 0, 0);
    s2 = __builtin_amdgcn_mfma_f32_16x16x32_bf16(kc1, qb1, s2, 0, 0, 0);

    // lane holds S'[k = kbase+8g+j][q = qbase+fr], j=0..7
    float sc[8];
    const int kb8 = kbase + 8 * g;
#pragma unroll
    for (int j = 0; j < 4; ++j) {
      sc[j]     = (kb8 + j     <= qg) ? s1[j] * 0.125f : -1e30f;
      sc[4 + j] = (kb8 + 4 + j <= qg) ? s2[j] * 0.125f : -1e30f;
    }
    float tmax = sc[0];
#pragma unroll
    for (int j = 1; j < 8; ++j) tmax = fmaxf(tmax, sc[j]);
    tmax = fmaxf(tmax, __shfl_xor(tmax, 16));
    tmax = fmaxf(tmax, __shfl_xor(tmax, 32));
    const float mnew = fmaxf(mrun, tmax);
    const float alpha = __expf(mrun - mnew);
    bf16x8 pb;
    float psum = 0.f;
#pragma unroll
    for (int j = 0; j < 8; ++j) {
      float p = __expf(sc[j] - mnew);
      psum += p;
      pb[j] = (__bf16)p;
    }
    psum += __shfl_xor(psum, 16);
    psum += __shfl_xor(psum, 32);
    lrun = lrun * alpha + psum;
    mrun = mnew;

    // PV: O^T[d][q] += V^T * P'   (A-frag: V[kbase+8g+j][dblk*16+fr])
    const unsigned short* vbase = QKV + (rowb + kbase + 8 * g) * LDQKV + 2048 + hoff + fr;
#pragma unroll
    for (int db = 0; db < 4; ++db) {
      union { unsigned short u[8]; bf16x8 v; } vt;
#pragma unroll
      for (int j = 0; j < 8; ++j) vt.u[j] = vbase[(long)j * LDQKV + db * 16];
#pragma unroll
      for (int r = 0; r < 4; ++r) acc[db][r] *= alpha;
      acc[db] = __builtin_amdgcn_mfma_f32_16x16x32_bf16(vt.v, pb, acc[db], 0, 0, 0);
    }
  }
  const float inv = 1.f / lrun;
  unsigned short* orow = O + (rowb + qbase + fr) * DM + hoff;
#pragma unroll
  for (int db = 0; db < 4; ++db)
#pragma unroll
    for (int r = 0; r < 4; ++r)
      orow[db * 16 + g * 4 + r] = f2bf(acc[db][r] * inv);
}

// ---------- SwiGLU: s = U*sigmoid(U)*G, zero the padded cols ----------
__global__ void swiglu_kernel(const unsigned short* __restrict__ UG, unsigned short* __restrict__ S) {
  int idx = blockIdx.x * 256 + threadIdx.x;  // 4096 * (2816/8)
  if (idx >= BT_ROWS * (DFFP / 8)) return;
  int r = idx / (DFFP / 8);
  int c8 = (idx % (DFFP / 8)) * 8;
  const unsigned short* u8 = UG + (long)r * (2 * DFFP) + c8;
  const uint4 uv = *reinterpret_cast<const uint4*>(u8);
  const uint4 gv = *reinterpret_cast<const uint4*>(u8 + DFFP);
  float uu[8] = {bf2f(uv.x & 0xffffu), bf2f(uv.x >> 16), bf2f(uv.y & 0xffffu), bf2f(uv.y >> 16),
                 bf2f(uv.z & 0xffffu), bf2f(uv.z >> 16), bf2f(uv.w & 0xffffu), bf2f(uv.w >> 16)};
  float gg[8] = {bf2f(gv.x & 0xffffu), bf2f(gv.x >> 16), bf2f(gv.y & 0xffffu), bf2f(gv.y >> 16),
                 bf2f(gv.z & 0xffffu), bf2f(gv.z >> 16), bf2f(gv.w & 0xffffu), bf2f(gv.w >> 16)};
  unsigned short ov[8];
#pragma unroll
  for (int j = 0; j < 8; ++j) {
    float v = (c8 + j < DFF) ? uu[j] * gg[j] / (1.f + __expf(-uu[j])) : 0.f;
    ov[j] = f2bf(v);
  }
  ushort4* dst = reinterpret_cast<ushort4*>(S + (long)r * DFFP + c8);
  dst[0] = make_ushort4(ov[0], ov[1], ov[2], ov[3]);
  dst[1] = make_ushort4(ov[4], ov[5], ov[6], ov[7]);
}

// ---------- workspace layout (117.5 MB, lifetime-reused) ----------
static constexpr size_t OFF_WQKV = 0;          // [3072,1024] bf16
static constexpr size_t OFF_WO   = 6291456;    // [1024,1024] bf16
static constexpr size_t OFF_W13  = 8388608;    // [5632,1024] bf16 (W1 pad | W3 pad)
static constexpr size_t OFF_W2   = 19922944;   // [1024,2816] bf16
static constexpr size_t OFF_H    = 25690112;   // [4096,1024] bf16 (h1 then h2)
static constexpr size_t OFF_X2   = 34078720;   // [4096,1024] f32
static constexpr size_t OFF_CT   = 50855936;   // [4096,32] f32
static constexpr size_t OFF_ST   = 51380224;   // [4096,32] f32
static constexpr size_t OFF_QKV  = 51904512;   // [4096,3072] bf16 (later: S [4096,2816])
static constexpr size_t OFF_HO   = 77070336;   // [4096,1024] bf16 (later: UG [4096,5632])

extern "C" void kernel_launch(void* const* d_in, const int* in_sizes, int n_in,
                              void* d_out, int out_size, void* d_ws, size_t ws_size,
                              hipStream_t stream) {
  const float* x  = (const float*)d_in[0];
  const int* tpos = (const int*)d_in[1];
  const float* WQ = (const float*)d_in[2];
  const float* WK = (const float*)d_in[3];
  const float* WV = (const float*)d_in[4];
  const float* WO = (const float*)d_in[5];
  const float* W1 = (const float*)d_in[6];
  const float* W2 = (const float*)d_in[7];
  const float* W3 = (const float*)d_in[8];
  const float* g1 = (const float*)d_in[9];
  const float* g2 = (const float*)d_in[10];
  float* out = (float*)d_out;

  char* ws = (char*)d_ws;
  unsigned short* Wqkv = (unsigned short*)(ws + OFF_WQKV);
  unsigned short* Wo   = (unsigned short*)(ws + OFF_WO);
  unsigned short* W13  = (unsigned short*)(ws + OFF_W13);
  unsigned short* W2p  = (unsigned short*)(ws + OFF_W2);
  unsigned short* hbuf = (unsigned short*)(ws + OFF_H);
  float* x2            = (float*)(ws + OFF_X2);
  float* ct            = (float*)(ws + OFF_CT);
  float* st            = (float*)(ws + OFF_ST);
  unsigned short* QKV  = (unsigned short*)(ws + OFF_QKV);
  unsigned short* Sbuf = (unsigned short*)(ws + OFF_QKV);  // reuse after attn
  unsigned short* Ho   = (unsigned short*)(ws + OFF_HO);
  unsigned short* UG   = (unsigned short*)(ws + OFF_HO);   // reuse after O-proj

  // weights -> bf16 (packed, padded)
  auto cvt = [&](const float* s, unsigned short* d, int Rs, int Cs, int Rd, int Cd) {
    long tot = (long)Rd * Cd;
    cvt_pad_kernel<<<(int)((tot + 255) / 256), 256, 0, stream>>>(s, d, Rs, Cs, tot, Cd);
  };
  cvt(WQ, Wqkv,              1024, 1024, 1024, 1024);
  cvt(WK, Wqkv + 1024 * 1024,1024, 1024, 1024, 1024);
  cvt(WV, Wqkv + 2048 * 1024,1024, 1024, 1024, 1024);
  cvt(WO, Wo,                1024, 1024, 1024, 1024);
  cvt(W1, W13,               DFF,  1024, DFFP, 1024);
  cvt(W3, W13 + DFFP * 1024, DFF,  1024, DFFP, 1024);
  cvt(W2, W2p,               1024, DFF,  1024, DFFP);

  // attention sublayer
  rmsnorm_kernel<<<BT_ROWS, 256, 0, stream>>>(x, g1, hbuf);
  trig_kernel<<<(BT_ROWS * 32) / 256, 256, 0, stream>>>(tpos, ct, st);
  gemm_bt<0><<<dim3(24, 32), 256, 0, stream>>>(hbuf, Wqkv, QKV, nullptr, BT_ROWS, 3072, 1024, LDQKV);
  rope_kernel<<<(BT_ROWS * 512) / 256, 256, 0, stream>>>(QKV, ct, st);
  attn_kernel<<<dim3(32, 32), 256, 0, stream>>>(QKV, Ho);
  gemm_bt<1><<<dim3(8, 32), 256, 0, stream>>>(Ho, Wo, x2, x, BT_ROWS, 1024, 1024, 1024);

  // FFN sublayer
  rmsnorm_kernel<<<BT_ROWS, 256, 0, stream>>>(x2, g2, hbuf);
  gemm_bt<0><<<dim3(44, 32), 256, 0, stream>>>(hbuf, W13, UG, nullptr, BT_ROWS, 2 * DFFP, 1024, 2 * DFFP);
  swiglu_kernel<<<(BT_ROWS * (DFFP / 8) + 255) / 256, 256, 0, stream>>>(UG, Sbuf);
  gemm_bt<1><<<dim3(8, 32), 256, 0, stream>>>(Sbuf, W2p, out, x2, BT_ROWS, 1024, DFFP, 1024);
}

// Round 2
// 333.016 us; speedup vs baseline: 1.1291x; 1.1291x over previous
//
#include <hip/hip_runtime.h>
#include <cstdint>

// ---------- sizes ----------
#define BT_ROWS 4096      // B*T
#define DM      1024
#define DFF     2730
#define DFFP    2816      // padded to /128
#define TSEQ    2048
#define LDQKV   3072

typedef float  f32x4  __attribute__((ext_vector_type(4)));
typedef __bf16 bf16x8 __attribute__((ext_vector_type(8)));

typedef __attribute__((address_space(1))) const unsigned int as1_uint;
typedef __attribute__((address_space(3))) unsigned int       as3_uint;

__device__ __forceinline__ unsigned short f2bf(float f) {
  union { float f; unsigned int u; } v; v.f = f;
  unsigned int u = v.u;
  return (unsigned short)((u + 0x7fffu + ((u >> 16) & 1u)) >> 16);  // RNE
}
__device__ __forceinline__ float bf2f(unsigned int b) {
  union { unsigned int u; float f; } v; v.u = b << 16;
  return v.f;
}

__device__ __forceinline__ void async_cp16(const void* g, void* l) {
  // 16B-wide global->LDS DMA; LDS dest is wave-uniform base + lane*16
  __builtin_amdgcn_global_load_lds((as1_uint*)(uintptr_t)g, (as3_uint*)(uintptr_t)l, 16, 0, 0);
}

// ---------- weight convert (+optional zero pad) ----------
__global__ void cvt_pad_kernel(const float* __restrict__ src, unsigned short* __restrict__ dst,
                               int Rs, int Cs, long total, int Cd) {
  long idx = (long)blockIdx.x * 256 + threadIdx.x;
  if (idx >= total) return;
  int r = (int)(idx / Cd), c = (int)(idx % Cd);
  float v = (r < Rs && c < Cs) ? src[(long)r * Cs + c] : 0.f;
  dst[idx] = f2bf(v);
}

// ---------- RMSNorm (fp32 in -> bf16 out), one block per row ----------
__global__ void rmsnorm_kernel(const float* __restrict__ x, const float* __restrict__ g,
                               unsigned short* __restrict__ out) {
  const int row = blockIdx.x, tid = threadIdx.x;
  const float4 xv = reinterpret_cast<const float4*>(x + (long)row * DM)[tid];
  float ss = xv.x * xv.x + xv.y * xv.y + xv.z * xv.z + xv.w * xv.w;
#pragma unroll
  for (int o = 32; o > 0; o >>= 1) ss += __shfl_xor(ss, o);
  __shared__ float wsum[4];
  if ((tid & 63) == 0) wsum[tid >> 6] = ss;
  __syncthreads();
  const float inv = rsqrtf((wsum[0] + wsum[1] + wsum[2] + wsum[3]) * (1.f / DM) + 1e-5f);
  const float4 gv = reinterpret_cast<const float4*>(g)[tid];
  ushort4 o4;
  o4.x = f2bf(xv.x * inv * gv.x);
  o4.y = f2bf(xv.y * inv * gv.y);
  o4.z = f2bf(xv.z * inv * gv.z);
  o4.w = f2bf(xv.w * inv * gv.w);
  reinterpret_cast<ushort4*>(out + (long)row * DM)[tid] = o4;
}

// ---------- RoPE cos/sin table ----------
__global__ void trig_kernel(const int* __restrict__ pos, float* __restrict__ ct, float* __restrict__ st) {
  int idx = blockIdx.x * 256 + threadIdx.x;
  if (idx >= BT_ROWS * 32) return;
  int r = idx >> 5, i = idx & 31;
  float f = powf(10000.f, -(float)(2 * i) * (1.f / 64.f));
  float ang = (float)pos[r] * f;
  float sv, cv;
  sincosf(ang, &sv, &cv);
  ct[idx] = cv; st[idx] = sv;
}

// ---------- RoPE applied in-place to Q,K halves of QKV (bf16) ----------
__global__ void rope_kernel(unsigned short* __restrict__ QKV,
                            const float* __restrict__ ct, const float* __restrict__ st) {
  int idx = blockIdx.x * 256 + threadIdx.x;  // over 4096*512 (row, head*pair)
  if (idx >= BT_ROWS * 512) return;
  int r = idx >> 9, p = idx & 511;
  int h = p >> 5, i = p & 31;
  float c = ct[r * 32 + i], s = st[r * 32 + i];
  unsigned int* base = reinterpret_cast<unsigned int*>(QKV + (long)r * LDQKV + h * 64 + 2 * i);
  unsigned int q01 = base[0];
  float x0 = bf2f(q01 & 0xffffu), x1 = bf2f(q01 >> 16);
  base[0] = (unsigned int)f2bf(c * x0 - s * x1) | ((unsigned int)f2bf(s * x0 + c * x1) << 16);
  unsigned int k01 = base[512];  // +1024 ushorts = K block
  float y0 = bf2f(k01 & 0xffffu), y1 = bf2f(k01 >> 16);
  base[512] = (unsigned int)f2bf(c * y0 - s * y1) | ((unsigned int)f2bf(s * y0 + c * y1) << 16);
}

// ---------- GEMM: C[M,N] = A[M,K] * B[N,K]^T  (bf16 in, fp32 acc) ----------
// EPI 0: bf16 store; EPI 1: fp32 store of acc + resid
template <int EPI>
__global__ __launch_bounds__(256) void gemm_bt(
    const unsigned short* __restrict__ A, const unsigned short* __restrict__ B,
    void* __restrict__ C, const float* __restrict__ resid,
    int M, int N, int K, int ldc) {
  __shared__ unsigned short As[128 * 32];
  __shared__ unsigned short Bs[128 * 32];
  const int tid = threadIdx.x;
  const int wid = tid >> 6;
  const int lane = tid & 63;
  const long rowBase = (long)blockIdx.y * 128;
  const long colBase = (long)blockIdx.x * 128;
  const int wm = (wid >> 1) * 64;
  const int wn = (wid & 1) * 64;
  const int l4 = lane >> 2;        // staging: row within 16-row chunk
  const int c8 = (lane & 3) * 8;   // staging: col (8 bf16 = 16B)
  const int fr = lane & 15;        // fragment row
  const int fg = lane >> 4;        // fragment k-group

  const f32x4 z4 = {0.f, 0.f, 0.f, 0.f};
  f32x4 acc[4][4];
#pragma unroll
  for (int m = 0; m < 4; ++m)
#pragma unroll
    for (int n = 0; n < 4; ++n) acc[m][n] = z4;

  const int nkt = K >> 5;
  for (int kt = 0; kt < nkt; ++kt) {
    if (kt) __syncthreads();  // previous compute done before LDS overwrite
    const long kOff = (long)kt * 32 + c8;
#pragma unroll
    for (int c = 0; c < 2; ++c) {
      const int chunk = c * 4 + wid;  // wave-uniform LDS base
      async_cp16(A + (rowBase + chunk * 16 + l4) * K + kOff, &As[chunk * 512]);
      async_cp16(B + (colBase + chunk * 16 + l4) * K + kOff, &Bs[chunk * 512]);
    }
    __syncthreads();  // compiler drains vmcnt(0) before s_barrier -> LDS ready
    bf16x8 af[4], bfr[4];
#pragma unroll
    for (int m = 0; m < 4; ++m)
      af[m] = *reinterpret_cast<const bf16x8*>(&As[(wm + m * 16 + fr) * 32 + fg * 8]);
#pragma unroll
    for (int n = 0; n < 4; ++n)
      bfr[n] = *reinterpret_cast<const bf16x8*>(&Bs[(wn + n * 16 + fr) * 32 + fg * 8]);
#pragma unroll
    for (int m = 0; m < 4; ++m)
#pragma unroll
      for (int n = 0; n < 4; ++n)
        acc[m][n] = __builtin_amdgcn_mfma_f32_16x16x32_bf16(af[m], bfr[n], acc[m][n], 0, 0, 0);
  }

  const int erow = fg * 4;  // C: col = lane&15, row = (lane>>4)*4 + reg
  if (EPI == 0) {
    unsigned short* Cp = (unsigned short*)C;
#pragma unroll
    for (int m = 0; m < 4; ++m) {
      const long r0 = rowBase + wm + m * 16 + erow;
#pragma unroll
      for (int n = 0; n < 4; ++n) {
        const long col = colBase + wn + n * 16 + fr;
#pragma unroll
        for (int r = 0; r < 4; ++r) Cp[(r0 + r) * ldc + col] = f2bf(acc[m][n][r]);
      }
    }
  } else {
    float* Cf = (float*)C;
#pragma unroll
    for (int m = 0; m < 4; ++m) {
      const long r0 = rowBase + wm + m * 16 + erow;
#pragma unroll
      for (int n = 0; n < 4; ++n) {
        const long col = colBase + wn + n * 16 + fr;
#pragma unroll
        for (int r = 0; r < 4; ++r) {
          const long o = (r0 + r) * ldc + col;
          Cf[o] = acc[m][n][r] + resid[o];
        }
      }
    }
  }
}

// ---------- flash attention, causal, 16 heads x d_k=64 ----------
// Swapped QK^T (S' = K*Q^T) with row-permuted K so P' lands directly in the
// PV MFMA's B-fragment layout. Block = 4 waves x 16 q-rows = 64 q-rows.
// K staged pre-permuted in LDS [32][72] (conflict-free b128 reads);
// V staged transposed in LDS [64][40] (conflict-free b128 reads).
// T14: next tile's global loads issued into regs before current compute.
#define KSTR 72
#define VSTR 40
__global__ __launch_bounds__(256) void attn_kernel(
    const unsigned short* __restrict__ QKV, unsigned short* __restrict__ O) {
  __shared__ unsigned short Ks[32 * KSTR];
  __shared__ unsigned short Vt[64 * VSTR];
  const int bh = blockIdx.x;
  const int b = bh >> 4, h = bh & 15;
  const int tid = threadIdx.x;
  const int wid = tid >> 6, lane = tid & 63;
  const int qblk = blockIdx.y;
  const int qbase = qblk * 64 + wid * 16;
  const int fr = lane & 15, g = lane >> 4;
  const long rowb = (long)b * TSEQ;
  const int hoff = h * 64;

  // staging thread->element maps
  const int ki = tid >> 3;                   // K lds row 0..31
  const int kcol = (tid & 7) * 8;            // K col (8 elems = 16B)
  const int kgrow = 8 * ((ki & 15) >> 2) + (ki & 3) + ((ki >> 4) << 2);  // permuted global k row
  const int vk = tid & 31;                   // V k index
  const int vd0 = (tid >> 5) * 8;            // V d col

  const unsigned short* qrow = QKV + (rowb + qbase + fr) * LDQKV + hoff + g * 8;
  const bf16x8 qb0 = *reinterpret_cast<const bf16x8*>(qrow);
  const bf16x8 qb1 = *reinterpret_cast<const bf16x8*>(qrow + 32);

  const f32x4 z4 = {0.f, 0.f, 0.f, 0.f};
  f32x4 acc[4];
#pragma unroll
  for (int d = 0; d < 4; ++d) acc[d] = z4;
  float mrun = -1e30f, lrun = 0.f;
  const int qg = qbase + fr;
  const int nkt = qblk * 2 + 2;

  const unsigned short* Kg = QKV + rowb * LDQKV + 1024 + hoff;
  const unsigned short* Vg = QKV + rowb * LDQKV + 2048 + hoff;

  // prologue: tile 0 into regs
  uint4 kreg = *reinterpret_cast<const uint4*>(Kg + (long)kgrow * LDQKV + kcol);
  uint4 vreg = *reinterpret_cast<const uint4*>(Vg + (long)vk * LDQKV + vd0);

  for (int kt = 0; kt < nkt; ++kt) {
    // LDS fill from regs
    *reinterpret_cast<uint4*>(&Ks[ki * KSTR + kcol]) = kreg;
    {
      union { uint4 u; unsigned short s[8]; } vv; vv.u = vreg;
#pragma unroll
      for (int j = 0; j < 8; ++j) Vt[(vd0 + j) * VSTR + vk] = vv.s[j];
    }
    __syncthreads();
    if (kt + 1 < nkt) {  // issue next tile's loads; latency hides under compute
      const long kb2 = (long)(kt + 1) * 32;
      kreg = *reinterpret_cast<const uint4*>(Kg + (kb2 + kgrow) * LDQKV + kcol);
      vreg = *reinterpret_cast<const uint4*>(Vg + (kb2 + vk) * LDQKV + vd0);
    }
    const int kbase = kt * 32;

    const bf16x8 ka0 = *reinterpret_cast<const bf16x8*>(&Ks[fr * KSTR + g * 8]);
    const bf16x8 ka1 = *reinterpret_cast<const bf16x8*>(&Ks[fr * KSTR + 32 + g * 8]);
    const bf16x8 kc0 = *reinterpret_cast<const bf16x8*>(&Ks[(16 + fr) * KSTR + g * 8]);
    const bf16x8 kc1 = *reinterpret_cast<const bf16x8*>(&Ks[(16 + fr) * KSTR + 32 + g * 8]);
    f32x4 s1 = z4, s2 = z4;
    s1 = __builtin_amdgcn_mfma_f32_16x16x32_bf16(ka0, qb0, s1, 0, 0, 0);
    s1 = __builtin_amdgcn_mfma_f32_16x16x32_bf16(ka1, qb1, s1, 0, 0, 0);
    s2 = __builtin_amdgcn_mfma_f32_16x16x32_bf16(kc0, qb0, s2, 0, 0, 0);
    s2 = __builtin_amdgcn_mfma_f32_16x16x32_bf16(kc1, qb1, s2, 0, 0, 0);

    // lane holds S'[k = kbase+8g+j][q = qbase+fr], j=0..7
    float sc[8];
    const int kb8 = kbase + 8 * g;
#pragma unroll
    for (int j = 0; j < 4; ++j) {
      sc[j]     = (kb8 + j     <= qg) ? s1[j] * 0.125f : -1e30f;
      sc[4 + j] = (kb8 + 4 + j <= qg) ? s2[j] * 0.125f : -1e30f;
    }
    float tmax = sc[0];
#pragma unroll
    for (int j = 1; j < 8; ++j) tmax = fmaxf(tmax, sc[j]);
    tmax = fmaxf(tmax, __shfl_xor(tmax, 16));
    tmax = fmaxf(tmax, __shfl_xor(tmax, 32));
    const float mnew = fmaxf(mrun, tmax);
    const float alpha = __expf(mrun - mnew);
    bf16x8 pb;
    float psum = 0.f;
#pragma unroll
    for (int j = 0; j < 8; ++j) {
      float p = __expf(sc[j] - mnew);
      psum += p;
      pb[j] = (__bf16)p;
    }
    psum += __shfl_xor(psum, 16);
    psum += __shfl_xor(psum, 32);
    lrun = lrun * alpha + psum;
    mrun = mnew;

    // PV: O^T[d][q] += V^T * P'  (A-frag: Vt[db*16+fr][8g+j] from LDS)
#pragma unroll
    for (int db = 0; db < 4; ++db) {
      const bf16x8 vfrag = *reinterpret_cast<const bf16x8*>(&Vt[(db * 16 + fr) * VSTR + g * 8]);
#pragma unroll
      for (int r = 0; r < 4; ++r) acc[db][r] *= alpha;
      acc[db] = __builtin_amdgcn_mfma_f32_16x16x32_bf16(vfrag, pb, acc[db], 0, 0, 0);
    }
    __syncthreads();  // protect LDS before next iteration's fill
  }

  const float inv = 1.f / lrun;
  unsigned short* orow = O + (rowb + qbase + fr) * DM + hoff;
#pragma unroll
  for (int db = 0; db < 4; ++db) {
    uint2 pk;
    pk.x = (unsigned int)f2bf(acc[db][0] * inv) | ((unsigned int)f2bf(acc[db][1] * inv) << 16);
    pk.y = (unsigned int)f2bf(acc[db][2] * inv) | ((unsigned int)f2bf(acc[db][3] * inv) << 16);
    *reinterpret_cast<uint2*>(orow + db * 16 + g * 4) = pk;
  }
}

// ---------- SwiGLU: s = U*sigmoid(U)*G, zero the padded cols ----------
__global__ void swiglu_kernel(const unsigned short* __restrict__ UG, unsigned short* __restrict__ S) {
  int idx = blockIdx.x * 256 + threadIdx.x;  // 4096 * (2816/8)
  if (idx >= BT_ROWS * (DFFP / 8)) return;
  int r = idx / (DFFP / 8);
  int c8 = (idx % (DFFP / 8)) * 8;
  const unsigned short* u8 = UG + (long)r * (2 * DFFP) + c8;
  const uint4 uv = *reinterpret_cast<const uint4*>(u8);
  const uint4 gv = *reinterpret_cast<const uint4*>(u8 + DFFP);
  float uu[8] = {bf2f(uv.x & 0xffffu), bf2f(uv.x >> 16), bf2f(uv.y & 0xffffu), bf2f(uv.y >> 16),
                 bf2f(uv.z & 0xffffu), bf2f(uv.z >> 16), bf2f(uv.w & 0xffffu), bf2f(uv.w >> 16)};
  float gg[8] = {bf2f(gv.x & 0xffffu), bf2f(gv.x >> 16), bf2f(gv.y & 0xffffu), bf2f(gv.y >> 16),
                 bf2f(gv.z & 0xffffu), bf2f(gv.z >> 16), bf2f(gv.w & 0xffffu), bf2f(gv.w >> 16)};
  unsigned short ov[8];
#pragma unroll
  for (int j = 0; j < 8; ++j) {
    float v = (c8 + j < DFF) ? uu[j] * gg[j] / (1.f + __expf(-uu[j])) : 0.f;
    ov[j] = f2bf(v);
  }
  ushort4* dst = reinterpret_cast<ushort4*>(S + (long)r * DFFP + c8);
  dst[0] = make_ushort4(ov[0], ov[1], ov[2], ov[3]);
  dst[1] = make_ushort4(ov[4], ov[5], ov[6], ov[7]);
}

// ---------- workspace layout (117.5 MB, lifetime-reused) ----------
static constexpr size_t OFF_WQKV = 0;          // [3072,1024] bf16
static constexpr size_t OFF_WO   = 6291456;    // [1024,1024] bf16
static constexpr size_t OFF_W13  = 8388608;    // [5632,1024] bf16 (W1 pad | W3 pad)
static constexpr size_t OFF_W2   = 19922944;   // [1024,2816] bf16
static constexpr size_t OFF_H    = 25690112;   // [4096,1024] bf16 (h1 then h2)
static constexpr size_t OFF_X2   = 34078720;   // [4096,1024] f32
static constexpr size_t OFF_CT   = 50855936;   // [4096,32] f32
static constexpr size_t OFF_ST   = 51380224;   // [4096,32] f32
static constexpr size_t OFF_QKV  = 51904512;   // [4096,3072] bf16 (later: S [4096,2816])
static constexpr size_t OFF_HO   = 77070336;   // [4096,1024] bf16 (later: UG [4096,5632])

extern "C" void kernel_launch(void* const* d_in, const int* in_sizes, int n_in,
                              void* d_out, int out_size, void* d_ws, size_t ws_size,
                              hipStream_t stream) {
  const float* x  = (const float*)d_in[0];
  const int* tpos = (const int*)d_in[1];
  const float* WQ = (const float*)d_in[2];
  const float* WK = (const float*)d_in[3];
  const float* WV = (const float*)d_in[4];
  const float* WO = (const float*)d_in[5];
  const float* W1 = (const float*)d_in[6];
  const float* W2 = (const float*)d_in[7];
  const float* W3 = (const float*)d_in[8];
  const float* g1 = (const float*)d_in[9];
  const float* g2 = (const float*)d_in[10];
  float* out = (float*)d_out;

  char* ws = (char*)d_ws;
  unsigned short* Wqkv = (unsigned short*)(ws + OFF_WQKV);
  unsigned short* Wo   = (unsigned short*)(ws + OFF_WO);
  unsigned short* W13  = (unsigned short*)(ws + OFF_W13);
  unsigned short* W2p  = (unsigned short*)(ws + OFF_W2);
  unsigned short* hbuf = (unsigned short*)(ws + OFF_H);
  float* x2            = (float*)(ws + OFF_X2);
  float* ct            = (float*)(ws + OFF_CT);
  float* st            = (float*)(ws + OFF_ST);
  unsigned short* QKV  = (unsigned short*)(ws + OFF_QKV);
  unsigned short* Sbuf = (unsigned short*)(ws + OFF_QKV);  // reuse after attn
  unsigned short* Ho   = (unsigned short*)(ws + OFF_HO);
  unsigned short* UG   = (unsigned short*)(ws + OFF_HO);   // reuse after O-proj

  // weights -> bf16 (packed, padded)
  auto cvt = [&](const float* s, unsigned short* d, int Rs, int Cs, int Rd, int Cd) {
    long tot = (long)Rd * Cd;
    cvt_pad_kernel<<<(int)((tot + 255) / 256), 256, 0, stream>>>(s, d, Rs, Cs, tot, Cd);
  };
  cvt(WQ, Wqkv,              1024, 1024, 1024, 1024);
  cvt(WK, Wqkv + 1024 * 1024,1024, 1024, 1024, 1024);
  cvt(WV, Wqkv + 2048 * 1024,1024, 1024, 1024, 1024);
  cvt(WO, Wo,                1024, 1024, 1024, 1024);
  cvt(W1, W13,               DFF,  1024, DFFP, 1024);
  cvt(W3, W13 + DFFP * 1024, DFF,  1024, DFFP, 1024);
  cvt(W2, W2p,               1024, DFF,  1024, DFFP);

  // attention sublayer
  rmsnorm_kernel<<<BT_ROWS, 256, 0, stream>>>(x, g1, hbuf);
  trig_kernel<<<(BT_ROWS * 32) / 256, 256, 0, stream>>>(tpos, ct, st);
  gemm_bt<0><<<dim3(24, 32), 256, 0, stream>>>(hbuf, Wqkv, QKV, nullptr, BT_ROWS, 3072, 1024, LDQKV);
  rope_kernel<<<(BT_ROWS * 512) / 256, 256, 0, stream>>>(QKV, ct, st);
  attn_kernel<<<dim3(32, 32), 256, 0, stream>>>(QKV, Ho);
  gemm_bt<1><<<dim3(8, 32), 256, 0, stream>>>(Ho, Wo, x2, x, BT_ROWS, 1024, 1024, 1024);

  // FFN sublayer
  rmsnorm_kernel<<<BT_ROWS, 256, 0, stream>>>(x2, g2, hbuf);
  gemm_bt<0><<<dim3(44, 32), 256, 0, stream>>>(hbuf, W13, UG, nullptr, BT_ROWS, 2 * DFFP, 1024, 2 * DFFP);
  swiglu_kernel<<<(BT_ROWS * (DFFP / 8) + 255) / 256, 256, 0, stream>>>(UG, Sbuf);
  gemm_bt<1><<<dim3(8, 32), 256, 0, stream>>>(Sbuf, W2p, out, x2, BT_ROWS, 1024, DFFP, 1024);
}